// Round 7
// baseline (83.252 us; speedup 1.0000x reference)
//
#include <hip/hip_runtime.h>

typedef __attribute__((ext_vector_type(8))) short short8;
typedef __attribute__((ext_vector_type(4))) float f32x4;
typedef __attribute__((ext_vector_type(8))) unsigned short ushort8;

__device__ __forceinline__ unsigned short f2bf(float x) {
  union { float f; unsigned u; } v; v.f = x;
  unsigned r = v.u + 0x7fffu + ((v.u >> 16) & 1u);   // round-to-nearest-even
  return (unsigned short)(r >> 16);
}

// ---------------- W[h][g] -> Wt[g][h] transpose + convert (512x512) ----------
__global__ __launch_bounds__(256) void wt_kernel(
    const float* __restrict__ W, unsigned short* __restrict__ Wt) {
  __shared__ float s[64][65];
  int g0 = blockIdx.x * 64, h0 = blockIdx.y * 64;
  int tx = threadIdx.x & 63, ty = threadIdx.x >> 6;
#pragma unroll
  for (int rr = 0; rr < 16; ++rr) {
    int h = ty * 16 + rr;
    s[h][tx] = W[(long)(h0 + h) * 512 + g0 + tx];
  }
  __syncthreads();
#pragma unroll
  for (int rr = 0; rr < 16; ++rr) {
    int g = ty * 16 + rr;
    Wt[(long)(g0 + g) * 512 + h0 + tx] = f2bf(s[tx][g]);
  }
}

// ---- Fused: gemm1 (blocks 0..511) + dec fp32->bf16 convert (blocks 512..4607)
__global__ __launch_bounds__(256) void gemm1_plus_cvtdec(
    const float* __restrict__ enc, const unsigned short* __restrict__ Wt,
    unsigned short* __restrict__ encW,
    const float* __restrict__ dec, unsigned short* __restrict__ dec_bf) {
  if (blockIdx.x >= 512) {
    int i = (blockIdx.x - 512) * 256 + threadIdx.x;
    const float4* p = (const float4*)(dec + (long)i * 8);
    float4 a = p[0], b = p[1];
    ushort8 o;
    o[0] = f2bf(a.x); o[1] = f2bf(a.y); o[2] = f2bf(a.z); o[3] = f2bf(a.w);
    o[4] = f2bf(b.x); o[5] = f2bf(b.y); o[6] = f2bf(b.z); o[7] = f2bf(b.w);
    *(ushort8*)(dec_bf + (long)i * 8) = o;
    return;
  }

  constexpr int K = 512, N = 512, BK = 32;
  __shared__ __align__(16) short As[128 * BK];
  __shared__ __align__(16) short Bs[128 * BK];

  const int g = blockIdx.x;
  const int work = (g & 7) * 64 + (g >> 3);      // bijective on [0,512)
  const int bxm = work >> 2, byn = work & 3;

  const int tid = threadIdx.x;
  const int wave = tid >> 6, lane = tid & 63;
  const int wm = wave >> 1, wn = wave & 1;
  const int r = lane & 15, q = lane >> 4;

  const float* Ab = enc + (long)bxm * 128 * K;
  const unsigned short* Bb = Wt + (long)byn * 128 * K;

  const int srow = tid >> 1, shalf = tid & 1;
  const float* arow = Ab + (long)srow * K + shalf * 16;

  f32x4 acc[4][4] = {};
  float4 av[4];
#pragma unroll
  for (int j = 0; j < 4; ++j) av[j] = ((const float4*)arow)[j];

  for (int kt = 0; kt < K; kt += BK) {
    ushort8 o0, o1;
    o0[0] = f2bf(av[0].x); o0[1] = f2bf(av[0].y); o0[2] = f2bf(av[0].z); o0[3] = f2bf(av[0].w);
    o0[4] = f2bf(av[1].x); o0[5] = f2bf(av[1].y); o0[6] = f2bf(av[1].z); o0[7] = f2bf(av[1].w);
    o1[0] = f2bf(av[2].x); o1[1] = f2bf(av[2].y); o1[2] = f2bf(av[2].z); o1[3] = f2bf(av[2].w);
    o1[4] = f2bf(av[3].x); o1[5] = f2bf(av[3].y); o1[6] = f2bf(av[3].z); o1[7] = f2bf(av[3].w);
    *(ushort8*)&As[srow * BK + shalf * 16 + 0] = o0;
    *(ushort8*)&As[srow * BK + shalf * 16 + 8] = o1;

#pragma unroll
    for (int j = 0; j < 2; ++j) {
      int c = (j * 4 + wave) * 64 + lane;
      int row = c >> 2;
      int coff = (c & 3) * 8;
      __builtin_amdgcn_global_load_lds(
          (const __attribute__((address_space(1))) void*)(Bb + (long)row * K + kt + coff),
          (__attribute__((address_space(3))) void*)(Bs + (j * 4 + wave) * 512),
          16, 0, 0);
    }
    __syncthreads();

    short8 af[4], bfr[4];
#pragma unroll
    for (int m = 0; m < 4; ++m)
      af[m] = *(const short8*)&As[(wm * 64 + m * 16 + r) * BK + q * 8];
#pragma unroll
    for (int n = 0; n < 4; ++n)
      bfr[n] = *(const short8*)&Bs[(wn * 64 + n * 16 + r) * BK + q * 8];

    if (kt + BK < K) {
      const float* ap = arow + kt + BK;
#pragma unroll
      for (int j = 0; j < 4; ++j) av[j] = ((const float4*)ap)[j];
    }

#pragma unroll
    for (int m = 0; m < 4; ++m)
#pragma unroll
      for (int n = 0; n < 4; ++n)
        acc[m][n] = __builtin_amdgcn_mfma_f32_16x16x32_bf16(af[m], bfr[n], acc[m][n], 0, 0, 0);
    __syncthreads();
  }

  const long rowbase = (long)bxm * 128 + wm * 64;
  const long colbase = (long)byn * 128 + wn * 64;
#pragma unroll
  for (int m = 0; m < 4; ++m)
#pragma unroll
    for (int n = 0; n < 4; ++n)
#pragma unroll
      for (int j = 0; j < 4; ++j) {
        long row = rowbase + m * 16 + q * 4 + j;
        long col = colbase + n * 16 + r;
        encW[row * (long)N + col] = f2bf(acc[m][n][j]);
      }
}

// ---------------- GEMM2: m97-structure 128x128, BK=32, 16KB LDS, 4 blk/CU ----
// scores[b][d][e] = sum_g dec_bf[b,d,g] * encW[b,e,g] + bias
// Verified-structure port (874-912 TF at 4096^3): gload_lds both operands,
// simple 2-barrier K-loop, no manual vmcnt/setprio. High occupancy (16 waves/CU)
// provides cross-block latency hiding for barrier drains + epilogue writes.
__global__ __launch_bounds__(256, 4) void gemm2_m97(
    const unsigned short* __restrict__ A,   // dec_bf [8*2048][512]
    const unsigned short* __restrict__ Bt,  // encW   [8*2048][512]
    float* __restrict__ C, const float* __restrict__ bias) {
  constexpr int K = 512, BK = 32;
  __shared__ __align__(16) short As[128 * BK];   // 8KB
  __shared__ __align__(16) short Bs[128 * BK];   // 8KB

  // XCD swizzle: 2048 blocks, 256/XCD -> one batch per XCD (dec+encW slice ~4MB L2)
  int flat = blockIdx.x;
  int sw = (flat & 7) * 256 + (flat >> 3);
  int z = sw >> 8, bx = (sw >> 4) & 15, by = sw & 15;

  const int tid = threadIdx.x;
  const int wave = tid >> 6, lane = tid & 63;
  const int wm = wave >> 1, wn = wave & 1;       // 2x2 waves, 64x64 out each
  const int r = lane & 15, q = lane >> 4;

  const unsigned short* Ab = A + ((long)z * 2048 + bx * 128) * 512;
  const unsigned short* Bb = Bt + ((long)z * 2048 + by * 128) * 512;

  f32x4 acc[4][4] = {};

  for (int kt = 0; kt < K; kt += BK) {
#pragma unroll
    for (int j = 0; j < 2; ++j) {
      int c = (j * 4 + wave) * 64 + lane;   // 16B-chunk id; row=c>>2, 4 chunks/row
      int row = c >> 2;
      int coff = (c & 3) * 8;
      __builtin_amdgcn_global_load_lds(
          (const __attribute__((address_space(1))) void*)(Ab + (long)row * K + kt + coff),
          (__attribute__((address_space(3))) void*)(As + (j * 4 + wave) * 512),
          16, 0, 0);
      __builtin_amdgcn_global_load_lds(
          (const __attribute__((address_space(1))) void*)(Bb + (long)row * K + kt + coff),
          (__attribute__((address_space(3))) void*)(Bs + (j * 4 + wave) * 512),
          16, 0, 0);
    }
    __syncthreads();

    short8 af[4], bfr[4];
#pragma unroll
    for (int m = 0; m < 4; ++m)
      af[m] = *(const short8*)&As[(wm * 64 + m * 16 + r) * BK + q * 8];
#pragma unroll
    for (int n = 0; n < 4; ++n)
      bfr[n] = *(const short8*)&Bs[(wn * 64 + n * 16 + r) * BK + q * 8];

#pragma unroll
    for (int m = 0; m < 4; ++m)
#pragma unroll
      for (int n = 0; n < 4; ++n)
        acc[m][n] = __builtin_amdgcn_mfma_f32_16x16x32_bf16(af[m], bfr[n], acc[m][n], 0, 0, 0);
    __syncthreads();
  }

  const float bv = bias[0];
  float* Cb = C + ((long)z * 2048 + bx * 128 + wm * 64) * 2048 + by * 128 + wn * 64;
#pragma unroll
  for (int m = 0; m < 4; ++m)
#pragma unroll
    for (int n = 0; n < 4; ++n)
#pragma unroll
      for (int j = 0; j < 4; ++j)
        Cb[(long)(m * 16 + q * 4 + j) * 2048 + n * 16 + r] = acc[m][n][j] + bv;
}

extern "C" void kernel_launch(void* const* d_in, const int* in_sizes, int n_in,
                              void* d_out, int out_size, void* d_ws, size_t ws_size,
                              hipStream_t stream) {
  const float* enc  = (const float*)d_in[0];  // [8,2048,512]
  const float* dec  = (const float*)d_in[1];  // [8,2048,512]
  const float* W    = (const float*)d_in[2];  // [1,512,512]
  const float* bias = (const float*)d_in[3];  // [1]
  float* out = (float*)d_out;                 // [8,2048,2048] fp32

  constexpr int Bn = 8, S = 2048, H = 512;
  constexpr long NE = (long)Bn * S * H;       // 8388608

  unsigned short* dec_bf = (unsigned short*)d_ws;        // 16.8 MB
  unsigned short* Wt     = dec_bf + NE;                  // 0.5 MB
  unsigned short* encW   = Wt + (long)H * H;             // 16.8 MB

  wt_kernel<<<dim3(8, 8), 256, 0, stream>>>(W, Wt);

  // gemm1 (512 blocks) + dec conversion (4096 blocks) in one launch
  gemm1_plus_cvtdec<<<dim3(512 + 4096, 1, 1), 256, 0, stream>>>(
      enc, Wt, encW, dec, dec_bf);

  // scores[b][d][e] = dec[b,d,:] . encW[b,e,:] + bias
  gemm2_m97<<<dim3(2048, 1, 1), 256, 0, stream>>>(dec_bf, encW, out, bias);
}